// Round 3
// baseline (776.116 us; speedup 1.0000x reference)
//
#include <hip/hip_runtime.h>
#include <stdint.h>

// ---------------- problem constants ----------------
#define T_TOK 8192      // B*S
#define DIN   1024
#define DOUT  1024
#define HID   2048
#define NEXP  8
#define MAXN  8192      // worst-case tokens per expert
#define NROUTED (2 * T_TOK)   // total routed rows (top-2) = 16384 always

typedef __attribute__((ext_vector_type(8))) short short8;   // 8 bf16 (4 VGPRs)
typedef __attribute__((ext_vector_type(4))) float floatx4;  // MFMA accumulator

__device__ __forceinline__ ushort f2bf(float f) {
    uint32_t u = __float_as_uint(f);
    uint32_t r = (u + 0x7fffu + ((u >> 16) & 1u)) >> 16;   // RNE
    return (ushort)r;
}

// async global->LDS, 16B per lane; LDS dst is wave-uniform base + lane*16
__device__ __forceinline__ void load_lds_16(const ushort* g, ushort* l) {
    __builtin_amdgcn_global_load_lds(
        (const __attribute__((address_space(1))) void*)g,
        (__attribute__((address_space(3))) void*)l, 16, 0, 0);
}

// ---------------- fp32 [R,C] -> bf16 [C,R] tiled transpose (z<8 expert, z==8 shared) ----
__global__ void transpose_bf16_kernel(const float* __restrict__ in_e, const float* __restrict__ in_s,
                                      ushort* __restrict__ out_e, ushort* __restrict__ out_s,
                                      int R, int C) {
    __shared__ float tile[64][65];
    const float* in; ushort* out;
    int zz = blockIdx.z;
    if (zz < NEXP) { in = in_e + (size_t)zz * R * C; out = out_e + (size_t)zz * R * C; }
    else           { in = in_s;                      out = out_s; }
    int r0 = blockIdx.y * 64, c0 = blockIdx.x * 64;
    int t  = threadIdx.x;
    int rr = t >> 4;            // 0..15
    int cc = (t & 15) * 4;      // 0..60
    for (int p = 0; p < 4; p++) {
        int row = rr + p * 16;
        float4 v = *(const float4*)(in + (size_t)(r0 + row) * C + c0 + cc);
        tile[row][cc + 0] = v.x; tile[row][cc + 1] = v.y;
        tile[row][cc + 2] = v.z; tile[row][cc + 3] = v.w;
    }
    __syncthreads();
    for (int p = 0; p < 4; p++) {
        int orow = rr + p * 16;   // output row = original col index
        ushort4 o;
        o.x = f2bf(tile[cc + 0][orow]);
        o.y = f2bf(tile[cc + 1][orow]);
        o.z = f2bf(tile[cc + 2][orow]);
        o.w = f2bf(tile[cc + 3][orow]);
        *(ushort4*)(out + (size_t)(c0 + orow) * R + r0 + cc) = o;
    }
}

// ---------------- gate + x->bf16 convert fused ----------------
__global__ void gate_compute_kernel(const float* __restrict__ x, const float* __restrict__ gw,
                                    const float* __restrict__ gb, float* __restrict__ ew_out,
                                    int* __restrict__ te1, int* __restrict__ te2,
                                    float* __restrict__ tw1, float* __restrict__ tw2,
                                    ushort* __restrict__ xb) {
    int gid  = blockIdx.x * blockDim.x + threadIdx.x;
    int t    = gid >> 6;
    int lane = threadIdx.x & 63;
    if (t >= T_TOK) return;
    float acc[8];
    #pragma unroll
    for (int e = 0; e < 8; e++) acc[e] = 0.f;
    const float* xrow = x + (size_t)t * DIN;
    ushort* xbrow = xb + (size_t)t * DIN;
    #pragma unroll
    for (int i = 0; i < 16; i++) {
        int d = lane + i * 64;
        float xv = xrow[d];
        xbrow[d] = f2bf(xv);                       // fused convert
        const float4* wr = (const float4*)(gw + (size_t)d * 8);
        float4 w0 = wr[0], w1 = wr[1];
        acc[0] += xv * w0.x; acc[1] += xv * w0.y; acc[2] += xv * w0.z; acc[3] += xv * w0.w;
        acc[4] += xv * w1.x; acc[5] += xv * w1.y; acc[6] += xv * w1.z; acc[7] += xv * w1.w;
    }
    #pragma unroll
    for (int e = 0; e < 8; e++)
        #pragma unroll
        for (int off = 32; off; off >>= 1) acc[e] += __shfl_xor(acc[e], off);
    if (lane == 0) {
        float l[8], mx = -1e30f;
        #pragma unroll
        for (int e = 0; e < 8; e++) { l[e] = acc[e] + gb[e]; mx = fmaxf(mx, l[e]); }
        float s = 0.f;
        #pragma unroll
        for (int e = 0; e < 8; e++) { l[e] = expf(l[e] - mx); s += l[e]; }
        float inv = 1.f / s;
        #pragma unroll
        for (int e = 0; e < 8; e++) { l[e] *= inv; ew_out[(size_t)t * 8 + e] = l[e]; }
        int i1 = 0;
        #pragma unroll
        for (int e = 1; e < 8; e++) if (l[e] > l[i1]) i1 = e;
        int i2 = (i1 == 0) ? 1 : 0;
        #pragma unroll
        for (int e = 0; e < 8; e++) if (e != i1 && l[e] > l[i2]) i2 = e;
        float s2 = l[i1] + l[i2];
        te1[t] = i1; tw1[t] = l[i1] / s2;
        te2[t] = i2; tw2[t] = l[i2] / s2;
    }
}

// ---------------- build expert lists ----------------
__global__ void build_lists_kernel(const int* __restrict__ te1, const int* __restrict__ te2,
                                   const float* __restrict__ tw1, const float* __restrict__ tw2,
                                   int* __restrict__ counts, int* __restrict__ etok,
                                   float* __restrict__ ew) {
    __shared__ int lcnt[NEXP];
    __shared__ int gbase[NEXP];
    int tid = threadIdx.x;
    int t = blockIdx.x * 256 + tid;
    if (tid < NEXP) lcnt[tid] = 0;
    __syncthreads();
    int e1 = te1[t], e2 = te2[t];
    float w1 = tw1[t], w2 = tw2[t];
    int r1 = atomicAdd(&lcnt[e1], 1);
    int r2 = atomicAdd(&lcnt[e2], 1);
    __syncthreads();
    if (tid < NEXP) gbase[tid] = atomicAdd(&counts[tid], lcnt[tid]);
    __syncthreads();
    int s1 = gbase[e1] + r1;
    etok[e1 * MAXN + s1] = t;
    ew  [e1 * MAXN + s1] = w1;
    int s2 = gbase[e2] + r2;
    etok[e2 * MAXN + s2] = t;
    ew  [e2 * MAXN + s2] = w2;
}

// ---------------- prefix + device-built LIVE tile lists ----------------
// tile pack: (z<<10) | (y<<4) | x ;  z==8 shared. Order: shared first, then experts;
// per z: x outer, y inner  -> consecutive tickets share the same 512KB B-panel (L2 reuse).
__global__ void prefix_tiles_kernel(const int* __restrict__ counts, int* __restrict__ offsets,
                                    int* __restrict__ tiles1, int* __restrict__ tiles2,
                                    int* __restrict__ meta) {
    if (threadIdx.x == 0 && blockIdx.x == 0) {
        int o = 0, ny[9];
        for (int e = 0; e < NEXP; e++) {
            offsets[e] = o; o += counts[e];
            ny[e] = (counts[e] + 255) >> 8;
        }
        offsets[8] = o;                // == NROUTED (sentinel for gather)
        ny[8] = T_TOK / 256;
        int i1 = 0, i2 = 0;
        for (int zi = 0; zi < 9; zi++) {
            int z = (zi == 0) ? 8 : zi - 1;
            for (int xx = 0; xx < HID / 256; xx++)
                for (int yy = 0; yy < ny[z]; yy++)
                    tiles1[i1++] = (z << 10) | (yy << 4) | xx;
        }
        for (int zi = 0; zi < 9; zi++) {
            int z = (zi == 0) ? 8 : zi - 1;
            for (int xx = 0; xx < DOUT / 256; xx++)
                for (int yy = 0; yy < ny[z]; yy++)
                    tiles2[i2++] = (z << 10) | (yy << 4) | xx;
        }
        meta[0] = i1; meta[1] = i2;
    }
}

// ---------------- gather routed activation rows: xg[p] = x_bf[etok(p)] ----------------
// grid = NROUTED blocks (constant), 256 threads; each block copies one 2KB row.
__global__ void gather_xg_kernel(const ushort* __restrict__ x_bf, ushort* __restrict__ xg,
                                 const int* __restrict__ offsets, const int* __restrict__ etok) {
    int p = blockIdx.x;
    int e = 0;
    #pragma unroll
    for (int i = 1; i < NEXP; i++) if (p >= offsets[i]) e = i;
    int tok = etok[e * MAXN + (p - offsets[e])];
    const ushort4* src = (const ushort4*)(x_bf + (size_t)tok * DIN);
    ushort4*       dst = (ushort4*)(xg + (size_t)p * DIN);
    dst[threadIdx.x] = src[threadIdx.x];     // 256 x 8B = 2KB
}

// ================= persistent ticketed 256x256 8-phase GEMM (per-GEMM, NO waits) ========
// 512 threads = 8 waves (2M x 4N); per-wave C = 128x64. LDS ring of 4 half-K slots
// (32 K each), counted vmcnt(8) (never 0 in main loop), setprio around MFMA clusters.
// All A sources are LINEAR now (xg is pre-gathered): staging is fully contiguous.
// MODE 0: A = xg (z<8, rows offsets[z]+m0..) or x_bf (z==8) -> relu -> h_buf / sh region
// MODE 1: A = h_buf (z<8) or sh region (z==8) -> (+bias [*w]) -> atomicAdd Out

#define STG(slot, j, kh) { \
    load_lds_16(srcA[j] + (size_t)(kh) * 32, dA[j] + (slot) * 8192); \
    load_lds_16(srcB[j] + (size_t)(kh) * 32, dB[j] + (slot) * 8192); }

#define LDA_FRAGS(slot, mh) { \
    const ushort* pa = &lA[(slot) * 8192 + (wave_m * 8 + (mh) * 4) * 512 + lane * 8]; \
    a[0] = *(const short8*)(pa +    0); a[1] = *(const short8*)(pa +  512); \
    a[2] = *(const short8*)(pa + 1024); a[3] = *(const short8*)(pa + 1536); }

#define LDB_FRAGS(slot) { \
    const ushort* pb = &lB[(slot) * 8192 + (wave_n * 4) * 512 + lane * 8]; \
    b[0] = *(const short8*)(pb +    0); b[1] = *(const short8*)(pb +  512); \
    b[2] = *(const short8*)(pb + 1024); b[3] = *(const short8*)(pb + 1536); }

#define MFMA16(mh) { \
    _Pragma("unroll") for (int mt = 0; mt < 4; ++mt) { \
      _Pragma("unroll") for (int nt = 0; nt < 4; ++nt) { \
        acc[(mh)*4+mt][nt] = __builtin_amdgcn_mfma_f32_16x16x32_bf16( \
            a[mt], b[nt], acc[(mh)*4+mt][nt], 0, 0, 0); } } }

#define PH_EVEN(slot, sslot, kh) { \
    LDA_FRAGS(slot, 0); LDB_FRAGS(slot); \
    STG(sslot, 0, kh); \
    __builtin_amdgcn_s_barrier(); \
    asm volatile("s_waitcnt lgkmcnt(0)" ::: "memory"); \
    __builtin_amdgcn_sched_barrier(0); \
    __builtin_amdgcn_s_setprio(1); \
    MFMA16(0); \
    __builtin_amdgcn_s_setprio(0); \
    __builtin_amdgcn_s_barrier(); \
    asm volatile("" ::: "memory"); }

#define PH_ODD(slot, sslot, kh) { \
    LDA_FRAGS(slot, 1); \
    STG(sslot, 1, kh); \
    __builtin_amdgcn_s_barrier(); \
    asm volatile("s_waitcnt lgkmcnt(0)" ::: "memory"); \
    __builtin_amdgcn_sched_barrier(0); \
    __builtin_amdgcn_s_setprio(1); \
    MFMA16(1); \
    __builtin_amdgcn_s_setprio(0); \
    asm volatile("s_waitcnt vmcnt(8)" ::: "memory"); \
    __builtin_amdgcn_s_barrier(); \
    asm volatile("" ::: "memory"); }

template <int MODE>
__global__ __launch_bounds__(512, 2)
void gemm_persist(const ushort* __restrict__ Ar, const ushort* __restrict__ As,
                  const ushort* __restrict__ Be, const ushort* __restrict__ Bs,
                  const float* __restrict__ biase, const float* __restrict__ biass,
                  ushort* __restrict__ He, ushort* __restrict__ Hs,
                  float* __restrict__ Out,
                  const int* __restrict__ counts, const int* __restrict__ offsets,
                  const int* __restrict__ etok, const float* __restrict__ ew,
                  const int* __restrict__ tiles, const int* __restrict__ meta,
                  int* __restrict__ ticket) {
    constexpr int K   = (MODE == 0) ? DIN : HID;
    constexpr int NN  = (MODE == 0) ? HID : DOUT;
    constexpr int NHc = K / 32;
    constexpr int J   = K / 128;

    __shared__ ushort lA[4 * 8192];   // 64 KB
    __shared__ ushort lB[4 * 8192];   // 64 KB
    __shared__ int    rowTok[256];
    __shared__ float  rowW[256];
    __shared__ int    sh_t;

    const int tid  = threadIdx.x;
    const int ntiles = meta[MODE];
    const int w = tid >> 6, lane = tid & 63;
    const int lm = lane & 15, lq = lane >> 4;
    const int wave_m = w >> 2, wave_n = w & 3;

    for (;;) {
        if (tid == 0) sh_t = atomicAdd(ticket, 1);
        __syncthreads();                         // also fences previous tile's rowTok use
        const int t = sh_t;
        if (t >= ntiles) return;

        const int tx = tiles[t];
        const int x  = tx & 15;
        const int y  = (tx >> 4) & 63;
        const int z  = (tx >> 10) & 15;
        const int m0 = y * 256, n0 = x * 256;

        int cnt, rowbase;
        const ushort* Aptr; const ushort* Bptr; const float* bptr;
        if (z < NEXP) {
            cnt = counts[z]; rowbase = offsets[z];
            Aptr = Ar; Bptr = Be + (size_t)z * NN * K; bptr = biase + (size_t)z * NN;
        } else {
            cnt = T_TOK; rowbase = 0;
            Aptr = As; Bptr = Bs; bptr = biass;
        }
        const int arow0 = rowbase + m0;          // linear A rows for this tile

        if constexpr (MODE == 1) {
            if (tid < 256 && z < NEXP) {
                int g = m0 + tid;
                rowTok[tid] = (g < cnt) ? etok[z * MAXN + g] : 0;
                rowW[tid]   = (g < cnt) ? ew[z * MAXN + g] : 0.f;
            }
        }
        __syncthreads();

        // producer pointers: wave w stages 1 KB blocks (j*8 + w) of A and B per slot
        const ushort* srcA[2]; const ushort* srcB[2];
        ushort* dA[2]; ushort* dB[2];
        #pragma unroll
        for (int j = 0; j < 2; ++j) {
            int blk = j * 8 + w;
            srcA[j] = Aptr + (size_t)(arow0 + blk * 16 + lm) * K + lq * 8;
            srcB[j] = Bptr + (size_t)(n0 + blk * 16 + lm) * K + lq * 8;
            dA[j] = &lA[blk * 512];
            dB[j] = &lB[blk * 512];
        }

        floatx4 acc[8][4];
        #pragma unroll
        for (int i = 0; i < 8; ++i)
            #pragma unroll
            for (int jj = 0; jj < 4; ++jj) acc[i][jj] = (floatx4){0.f, 0.f, 0.f, 0.f};

        short8 a[4], b[4];

        // prologue: stage slots 0,1,2 ; retire slot0's loads, keep 8 in flight
        STG(0, 0, 0); STG(0, 1, 0);
        STG(1, 0, 1); STG(1, 1, 1);
        STG(2, 0, 2); STG(2, 1, 2);
        asm volatile("s_waitcnt vmcnt(8)" ::: "memory");
        __builtin_amdgcn_s_barrier();
        asm volatile("" ::: "memory");

        for (int j = 0; j < J; ++j) {
            int k4 = 4 * j;
            int kh3 = k4 + 3; if (kh3 > NHc - 1) kh3 = NHc - 1;   // clamp keeps vmcnt
            int kh4 = k4 + 4; if (kh4 > NHc - 1) kh4 = NHc - 1;   // bookkeeping exact
            int kh5 = k4 + 5; if (kh5 > NHc - 1) kh5 = NHc - 1;   // at the K tail
            int kh6 = k4 + 6; if (kh6 > NHc - 1) kh6 = NHc - 1;
            PH_EVEN(0, 3, kh3);
            PH_ODD (0, 3, kh3);
            PH_EVEN(1, 0, kh4);
            PH_ODD (1, 0, kh4);
            PH_EVEN(2, 1, kh5);
            PH_ODD (2, 1, kh5);
            PH_EVEN(3, 2, kh6);
            PH_ODD (3, 2, kh6);
        }

        asm volatile("s_waitcnt vmcnt(0)" ::: "memory");   // drain trailing clamped loads

        // epilogue: D[row = lq*4 + r][col = lane&15] per 16x16 fragment
        const int wn0 = wave_n * 64;
        #pragma unroll
        for (int mt8 = 0; mt8 < 8; ++mt8) {
            const int rl0 = wave_m * 128 + mt8 * 16 + lq * 4;
            #pragma unroll
            for (int nt = 0; nt < 4; ++nt) {
                const int col = n0 + wn0 + nt * 16 + lm;
                const float bv = bptr[col];
                #pragma unroll
                for (int r = 0; r < 4; ++r) {
                    const int rl = rl0 + r;
                    const int g  = m0 + rl;
                    float v = acc[mt8][nt][r];
                    if constexpr (MODE == 0) {
                        v = fmaxf(v + bv, 0.f);
                        if (z < NEXP) {
                            if (g < cnt) He[(size_t)(rowbase + g) * HID + col] = f2bf(v);
                        } else {
                            Hs[(size_t)g * HID + col] = f2bf(v);
                        }
                    } else {
                        if (z < NEXP) {
                            if (g < cnt)
                                atomicAdd(&Out[(size_t)rowTok[rl] * DOUT + col], (v + bv) * rowW[rl]);
                        } else {
                            atomicAdd(&Out[(size_t)g * DOUT + col], v + bv);
                        }
                    }
                }
            }
        }
    }
}

// ---------------- launch ----------------
extern "C" void kernel_launch(void* const* d_in, const int* in_sizes, int n_in,
                              void* d_out, int out_size, void* d_ws, size_t ws_size,
                              hipStream_t stream) {
    const float* x   = (const float*)d_in[0];
    const float* gw  = (const float*)d_in[1];
    const float* gb  = (const float*)d_in[2];
    const float* ew1 = (const float*)d_in[3];
    const float* eb1 = (const float*)d_in[4];
    const float* ew2 = (const float*)d_in[5];
    const float* eb2 = (const float*)d_in[6];
    const float* sw1 = (const float*)d_in[7];
    const float* sb1 = (const float*)d_in[8];
    const float* sw2 = (const float*)d_in[9];
    const float* sb2 = (const float*)d_in[10];

    float* out_final = (float*)d_out;
    float* out_ew    = out_final + (size_t)T_TOK * DOUT;

    char* ws = (char*)d_ws;
    size_t off = 0;
    auto alloc = [&](size_t bytes) -> void* {
        void* p = ws + off;
        off += (bytes + 255) & ~(size_t)255;
        return p;
    };
    ushort* x_bf    = (ushort*)alloc((size_t)T_TOK * DIN * 2);
    ushort* xg      = (ushort*)alloc((size_t)(NROUTED + 256) * DIN * 2);   // +slack rows
    ushort* ew1t    = (ushort*)alloc((size_t)NEXP * HID * DIN * 2);
    ushort* ew2t    = (ushort*)alloc((size_t)NEXP * DOUT * HID * 2);
    ushort* sw1t    = (ushort*)alloc((size_t)HID * DIN * 2);
    ushort* sw2t    = (ushort*)alloc((size_t)DOUT * HID * 2);
    // h_buf: routed rows [0, NROUTED) ; shared rows [NROUTED, NROUTED+T_TOK)
    // (shared region doubles as overrun slack for routed partial tiles)
    ushort* h_buf   = (ushort*)alloc((size_t)(NROUTED + T_TOK) * HID * 2);
    ushort* sh_buf  = h_buf + (size_t)NROUTED * HID;
    // control block: counts(8) + tickets(8) -> single memset
    int*    ctrl    = (int*)alloc(16 * 4);
    int*    counts  = ctrl;
    int*    ticket1 = ctrl + 8;
    int*    ticket2 = ctrl + 9;
    int*    offsets = (int*)alloc(16 * 4);          // 9 used
    int*    tiles1  = (int*)alloc(2048 * 4);
    int*    tiles2  = (int*)alloc(2048 * 4);
    int*    meta    = (int*)alloc(256);
    int*    etok    = (int*)alloc((size_t)NEXP * MAXN * 4);
    float*  ew      = (float*)alloc((size_t)NEXP * MAXN * 4);
    int*    te1     = (int*)alloc((size_t)T_TOK * 4);
    int*    te2     = (int*)alloc((size_t)T_TOK * 4);
    float*  tw1     = (float*)alloc((size_t)T_TOK * 4);
    float*  tw2     = (float*)alloc((size_t)T_TOK * 4);

    hipMemsetAsync(d_out, 0, (size_t)T_TOK * DOUT * 4, stream);   // final region only
    hipMemsetAsync(ctrl, 0, 16 * 4, stream);                      // counts + tickets

    transpose_bf16_kernel<<<dim3(HID / 64, DIN / 64, NEXP + 1), 256, 0, stream>>>(
        ew1, sw1, ew1t, sw1t, DIN, HID);
    transpose_bf16_kernel<<<dim3(DOUT / 64, HID / 64, NEXP + 1), 256, 0, stream>>>(
        ew2, sw2, ew2t, sw2t, HID, DOUT);

    gate_compute_kernel<<<T_TOK / 4, 256, 0, stream>>>(x, gw, gb, out_ew, te1, te2, tw1, tw2, x_bf);
    build_lists_kernel<<<T_TOK / 256, 256, 0, stream>>>(te1, te2, tw1, tw2, counts, etok, ew);
    prefix_tiles_kernel<<<1, 64, 0, stream>>>(counts, offsets, tiles1, tiles2, meta);
    gather_xg_kernel<<<NROUTED, 256, 0, stream>>>(x_bf, xg, offsets, etok);

    // persistent live-tile GEMM1 (routed + shared fused), then GEMM2 — no inter-block waits
    gemm_persist<0><<<256, 512, 0, stream>>>(
        xg, x_bf, ew1t, sw1t, eb1, sb1, h_buf, sh_buf, nullptr,
        counts, offsets, etok, ew, tiles1, meta, ticket1);
    gemm_persist<1><<<256, 512, 0, stream>>>(
        h_buf, sh_buf, ew2t, sw2t, eb2, sb2, nullptr, nullptr, out_final,
        counts, offsets, etok, ew, tiles2, meta, ticket2);
}